// Round 9
// baseline (374.488 us; speedup 1.0000x reference)
//
#include <hip/hip_runtime.h>
#include <math.h>

#define TT 40          // total query tokens
#define HKn 8
#define Gn 2
#define HID 3072
#define NCHUNK 16
#define CHUNKT 128

// ---------------- k1q: Q projection partial GEMM ----------------
// grid 256 = 16 col-tiles(256) * 16 k-splits(192), block 256
__global__ __launch_bounds__(256) void k1q(
    const float* __restrict__ hs, const float* __restrict__ Wq,
    float* __restrict__ part1q) {
  const int tile = blockIdx.x & 15;
  const int ks = blockIdx.x >> 4;
  const int c0 = tile << 8;
  const int kbase = ks * 192;
  const int cq = (threadIdx.x & 63) << 2;
  const int r0 = (threadIdx.x >> 6) * 10;
  __shared__ float h_lds[40][64];
  float acc[10][4];
#pragma unroll
  for (int r = 0; r < 10; ++r) { acc[r][0]=0.f; acc[r][1]=0.f; acc[r][2]=0.f; acc[r][3]=0.f; }
  for (int kc = 0; kc < 192; kc += 64) {
    __syncthreads();
    for (int i = threadIdx.x; i < 2560; i += 256) {
      int t = i >> 6, kk = i & 63;
      h_lds[t][kk] = hs[t * HID + kbase + kc + kk];
    }
    __syncthreads();
    const float* wp = Wq + (size_t)(kbase + kc) * 4096 + c0 + cq;
#pragma unroll 8
    for (int kk = 0; kk < 64; ++kk) {
      float4 w4 = *reinterpret_cast<const float4*>(wp + (size_t)kk * 4096);
#pragma unroll
      for (int r = 0; r < 10; ++r) {
        float h = h_lds[r0 + r][kk];
        acc[r][0] = fmaf(h, w4.x, acc[r][0]);
        acc[r][1] = fmaf(h, w4.y, acc[r][1]);
        acc[r][2] = fmaf(h, w4.z, acc[r][2]);
        acc[r][3] = fmaf(h, w4.w, acc[r][3]);
      }
    }
  }
#pragma unroll
  for (int r = 0; r < 10; ++r) {
    int t = r0 + r;
    float4 v = make_float4(acc[r][0], acc[r][1], acc[r][2], acc[r][3]);
    *reinterpret_cast<float4*>(&part1q[(size_t)(ks * TT + t) * 4096 + c0 + cq]) = v;
  }
}

// ---------------- k2q: reduce 16 splits + RoPE + scale -> qbuf ----------------
// grid 640 = 40 tokens * 16 tiles, block 256
__global__ __launch_bounds__(256) void k2q(
    const float* __restrict__ part1q, const float* __restrict__ inv_freq,
    const int* __restrict__ pos_ids, float* __restrict__ qbuf) {
  const int t = blockIdx.x >> 4;
  const int tile = blockIdx.x & 15;
  const int c = (tile << 8) + threadIdx.x;
  float s = 0.f;
#pragma unroll
  for (int ks = 0; ks < 16; ++ks) s += part1q[(size_t)(ks * TT + t) * 4096 + c];
  __shared__ float sl[256];
  sl[threadIdx.x] = s;
  __syncthreads();
  const int d = threadIdx.x;
  float fr = (float)pos_ids[t] * inv_freq[d & 127];
  float cs = cosf(fr), sn = sinf(fr);
  float v = (d < 128) ? (sl[d] * cs - sl[d + 128] * sn)
                      : (sl[d] * cs + sl[d - 128] * sn);
  qbuf[t * 4096 + (tile << 8) + d] = v * 0.0625f;  // fold 1/sqrt(256)
}

// ---------------- kA: fused {Wk/Wv GEMM} + {history flash-attention} ----------------
// blocks [0,96): k1kv (16 tiles * 6 k-splits of 512)
// blocks [96, 96+2048): k3hist (b*hk*chunk over HISTORY tokens only)
__global__ __launch_bounds__(256) void kA(
    const float* __restrict__ hs, const float* __restrict__ Wk,
    const float* __restrict__ Wv, float* __restrict__ part1kv,
    const float* __restrict__ qbuf, const float* __restrict__ k_cache,
    const float* __restrict__ v_cache, const int* __restrict__ blk_off,
    const int* __restrict__ q_start, const int* __restrict__ q_lens,
    const int* __restrict__ kv_lens,
    float* __restrict__ part_o, float* __restrict__ part_ml) {
  __shared__ __align__(16) char smem[17440];
  const int tid = threadIdx.x;

  if (blockIdx.x < 96) {
    // ===== k1kv path =====
    const int tile = blockIdx.x & 15;            // 0..7 = Wk heads, 8..15 = Wv heads
    const int ks = blockIdx.x >> 4;              // 0..5
    const float* W = (tile < 8) ? Wk : Wv;
    const int cw0 = (tile & 7) << 8;
    const int kbase = ks << 9;                   // *512
    const int cq = (tid & 63) << 2;
    const int r0 = (tid >> 6) * 10;
    float (*h_lds)[64] = (float (*)[64])smem;
    float acc[10][4];
#pragma unroll
    for (int r = 0; r < 10; ++r) { acc[r][0]=0.f; acc[r][1]=0.f; acc[r][2]=0.f; acc[r][3]=0.f; }
    for (int kc = 0; kc < 512; kc += 64) {
      __syncthreads();
      for (int i = tid; i < 2560; i += 256) {
        int t = i >> 6, kk = i & 63;
        h_lds[t][kk] = hs[t * HID + kbase + kc + kk];
      }
      __syncthreads();
      const float* wp = W + (size_t)(kbase + kc) * 2048 + cw0 + cq;
#pragma unroll 8
      for (int kk = 0; kk < 64; ++kk) {
        float4 w4 = *reinterpret_cast<const float4*>(wp + (size_t)kk * 2048);
#pragma unroll
        for (int r = 0; r < 10; ++r) {
          float h = h_lds[r0 + r][kk];
          acc[r][0] = fmaf(h, w4.x, acc[r][0]);
          acc[r][1] = fmaf(h, w4.y, acc[r][1]);
          acc[r][2] = fmaf(h, w4.z, acc[r][2]);
          acc[r][3] = fmaf(h, w4.w, acc[r][3]);
        }
      }
    }
#pragma unroll
    for (int r = 0; r < 10; ++r) {
      int t = r0 + r;
      float4 v = make_float4(acc[r][0], acc[r][1], acc[r][2], acc[r][3]);
      *reinterpret_cast<float4*>(&part1kv[(size_t)(ks * TT + t) * 4096 + (tile << 8) + cq]) = v;
    }
    return;
  }

  // ===== k3hist path =====
  const int v = blockIdx.x - 96;
  const int chunk = v & 15;
  const int hk = (v >> 4) & 7;
  const int b = v >> 7;
  const int q_cnt = q_lens[b];
  const int hist = kv_lens[b] - q_cnt;
  const int cs0 = chunk * CHUNKT;
  if (cs0 >= hist) return;
  const int q0 = q_start[b];
  const int nq = q_cnt * 2;

  float (*q_lds)[256] = (float (*)[256])smem;            //  8192 B
  float (*S2)[128][8] = (float (*)[128][8])(smem + 8192);//  8192 B
  float (*red)[8]     = (float (*)[8])(smem + 16384);    //  1024 B
  float* Mg           = (float*)(smem + 17408);          //    32 B

  const int w = tid >> 6;
  const int lane = tid & 63;
  const int tp = lane & 7;
  const int qd = lane >> 3;

  const int bi = (b << 5) + (cs0 >> 6);
  const int blk0v = blk_off[bi];
  const int blk1v = blk_off[bi + 1];
  const float* kb0 = k_cache + ((size_t)blk0v << 17) + ((size_t)hk << 8);
  const float* kb1 = k_cache + ((size_t)blk1v << 17) + ((size_t)hk << 8);
  const float* vb0 = v_cache + ((size_t)blk0v << 17) + ((size_t)hk << 8);
  const float* vb1 = v_cache + ((size_t)blk1v << 17) + ((size_t)hk << 8);

  // stage Q (scale already folded)
  for (int i = tid; i < 2048; i += 256) {
    int qv = i >> 8, d = i & 255;
    int qtok = min(qv >> 1, q_cnt - 1);
    q_lds[qv][d] = qbuf[(size_t)(q0 + qtok) * 4096 + (hk * Gn + (qv & 1)) * 256 + d];
  }
  __syncthreads();

  const int sBeg = cs0 + (w << 5);

  // ---- score phase: lane owns 4 tokens x 32 interleaved dims ----
  const float* kr[4];
#pragma unroll
  for (int tt = 0; tt < 4; ++tt) {
    int s = sBeg + (tp << 2) + tt;
    int sc = s < hist ? s : hist - 1;           // clamp; masked in softmax
    kr[tt] = (((sc & 64) ? kb1 : kb0) + ((size_t)(sc & 63) << 11)) + (qd << 2);
  }
  float acc[4][8];
#pragma unroll
  for (int tt = 0; tt < 4; ++tt)
#pragma unroll
    for (int qv = 0; qv < 8; ++qv) acc[tt][qv] = 0.f;
#pragma unroll
  for (int c = 0; c < 8; ++c) {
    float4 kf[4];
#pragma unroll
    for (int tt = 0; tt < 4; ++tt)
      kf[tt] = *reinterpret_cast<const float4*>(kr[tt] + (c << 5));
#pragma unroll
    for (int qv = 0; qv < 8; ++qv) {
      float4 qf = *reinterpret_cast<const float4*>(&q_lds[qv][(qd << 2) + (c << 5)]);
#pragma unroll
      for (int tt = 0; tt < 4; ++tt) {
        acc[tt][qv] = fmaf(qf.x, kf[tt].x, acc[tt][qv]);
        acc[tt][qv] = fmaf(qf.y, kf[tt].y, acc[tt][qv]);
        acc[tt][qv] = fmaf(qf.z, kf[tt].z, acc[tt][qv]);
        acc[tt][qv] = fmaf(qf.w, kf[tt].w, acc[tt][qv]);
      }
    }
  }
#pragma unroll
  for (int tt = 0; tt < 4; ++tt)
#pragma unroll
    for (int qv = 0; qv < 8; ++qv) {
      float val = acc[tt][qv];
      val += __shfl_xor(val, 8);
      val += __shfl_xor(val, 16);
      acc[tt][qv] = val;
    }
  if ((lane & 24) == 0) {
    const int h = lane >> 5;
#pragma unroll
    for (int tt = 0; tt < 4; ++tt) {
      int srel = (w << 5) + (tp << 2) + tt;
      *reinterpret_cast<float4*>(&S2[h][srel][0]) =
          make_float4(acc[tt][0], acc[tt][1], acc[tt][2], acc[tt][3]);
      *reinterpret_cast<float4*>(&S2[h][srel][4]) =
          make_float4(acc[tt][4], acc[tt][5], acc[tt][6], acc[tt][7]);
    }
  }
  __syncthreads();

  // ---- softmax over the chunk (history: no causal mask, only tail mask) ----
  const int qv2 = tid & 7;
  const int grp = tid >> 3;
  float sv[4];
  {
    float mloc = -1e30f;
#pragma unroll
    for (int t = 0; t < 4; ++t) {
      int sl = (grp << 2) + t;
      float val = S2[0][sl][qv2] + S2[1][sl][qv2];
      val = (cs0 + sl < hist) ? val : -1e30f;
      sv[t] = val;
      mloc = fmaxf(mloc, val);
    }
    red[grp][qv2] = mloc;
  }
  __syncthreads();
  if (tid < 8) {
    float M = -1e30f;
#pragma unroll
    for (int i = 0; i < 32; ++i) M = fmaxf(M, red[i][tid]);
    Mg[tid] = M;
  }
  __syncthreads();
  {
    float M = Mg[qv2];
    float lloc = 0.f;
#pragma unroll
    for (int t = 0; t < 4; ++t) {
      float p = __expf(sv[t] - M);
      S2[0][(grp << 2) + t][qv2] = p;
      lloc += p;
    }
    red[grp][qv2] = lloc;
  }
  __syncthreads();
  if (tid < 8) {
    float L = 0.f;
#pragma unroll
    for (int i = 0; i < 32; ++i) L += red[i][tid];
    int pidx = (((b * HKn + hk) * NCHUNK + chunk) << 3) + tid;
    part_ml[pidx * 2] = Mg[tid];
    part_ml[pidx * 2 + 1] = L;
  }
  __syncthreads();

  // ---- PV: wave w owns qv pair (2w,2w+1) over all 128 chunk tokens ----
  const int qp = w << 1;
  const int d4 = lane << 2;
  float4 a0 = make_float4(0.f, 0.f, 0.f, 0.f);
  float4 a1 = make_float4(0.f, 0.f, 0.f, 0.f);
#pragma unroll 4
  for (int s2 = 0; s2 < 128; ++s2) {
    int sc = cs0 + s2;
    sc = sc < hist ? sc : hist - 1;   // p==0 masks the clamped rows
    const float* vrow = ((sc & 64) ? vb1 : vb0) + ((size_t)(sc & 63) << 11);
    float4 vf = *reinterpret_cast<const float4*>(vrow + d4);
    float2 pp = *reinterpret_cast<const float2*>(&S2[0][s2][qp]);
    a0.x = fmaf(pp.x, vf.x, a0.x); a0.y = fmaf(pp.x, vf.y, a0.y);
    a0.z = fmaf(pp.x, vf.z, a0.z); a0.w = fmaf(pp.x, vf.w, a0.w);
    a1.x = fmaf(pp.y, vf.x, a1.x); a1.y = fmaf(pp.y, vf.y, a1.y);
    a1.z = fmaf(pp.y, vf.z, a1.z); a1.w = fmaf(pp.y, vf.w, a1.w);
  }
  int pidxb = (((b * HKn + hk) * NCHUNK + chunk) << 3) + qp;
  *reinterpret_cast<float4*>(&part_o[(size_t)pidxb * 256 + d4]) = a0;
  *reinterpret_cast<float4*>(&part_o[(size_t)(pidxb + 1) * 256 + d4]) = a1;
}

// ---------------- k2kv: reduce 6 splits + RoPE(K) -> kbuf, vbuf ----------------
// grid 640 = 40 tokens * 16 tiles
__global__ __launch_bounds__(256) void k2kv(
    const float* __restrict__ part1kv, const float* __restrict__ inv_freq,
    const int* __restrict__ pos_ids,
    float* __restrict__ kbuf, float* __restrict__ vbuf) {
  const int t = blockIdx.x >> 4;
  const int tile = blockIdx.x & 15;
  const int c = (tile << 8) + threadIdx.x;
  float s = 0.f;
#pragma unroll
  for (int ks = 0; ks < 6; ++ks) s += part1kv[(size_t)(ks * TT + t) * 4096 + c];
  __shared__ float sl[256];
  sl[threadIdx.x] = s;
  __syncthreads();
  if (tile < 8) {
    const int d = threadIdx.x;
    float fr = (float)pos_ids[t] * inv_freq[d & 127];
    float cs = cosf(fr), sn = sinf(fr);
    float v = (d < 128) ? (sl[d] * cs - sl[d + 128] * sn)
                        : (sl[d] * cs + sl[d - 128] * sn);
    kbuf[t * 2048 + (tile << 8) + d] = v;
  } else {
    vbuf[t * 2048 + ((tile - 8) << 8) + threadIdx.x] = s;
  }
}

// ---------------- k3new: merge new-token contributions into last hist partial ----
// grid 128 = b(16)*hk(8), block 256
__global__ __launch_bounds__(256) void k3new(
    const float* __restrict__ qbuf, const float* __restrict__ kbuf,
    const float* __restrict__ vbuf, const int* __restrict__ q_start,
    const int* __restrict__ q_lens, const int* __restrict__ kv_lens,
    float* __restrict__ part_o, float* __restrict__ part_ml) {
  const int hk = blockIdx.x & 7;
  const int b = blockIdx.x >> 3;
  const int q_cnt = q_lens[b];
  const int hist = kv_lens[b] - q_cnt;
  const int q0 = q_start[b];
  const int nq = q_cnt * 2;
  const int npH = (hist + 127) >> 7;
  const int slot = npH - 1;

  __shared__ float S[4][8];
  __shared__ float pf[4][8];
  __shared__ float e1s[8];

  const int tid = threadIdx.x;
  const int w = tid >> 6;
  const int lane = tid & 63;

  // scores: wave w = new token j (j < q_cnt)
  if (w < q_cnt) {
    const int qv = lane & 7;
    const int dg = lane >> 3;
    const float* kp = kbuf + (size_t)(q0 + w) * 2048 + (hk << 8) + (dg << 5);
    const float* qp = qbuf + (size_t)(q0 + min(qv >> 1, q_cnt - 1)) * 4096
                    + (hk * Gn + (qv & 1)) * 256 + (dg << 5);
    float sc = 0.f;
#pragma unroll
    for (int j = 0; j < 8; ++j) {
      float4 kf = *reinterpret_cast<const float4*>(kp + (j << 2));
      float4 qf = *reinterpret_cast<const float4*>(qp + (j << 2));
      sc = fmaf(qf.x, kf.x, sc); sc = fmaf(qf.y, kf.y, sc);
      sc = fmaf(qf.z, kf.z, sc); sc = fmaf(qf.w, kf.w, sc);
    }
    sc += __shfl_xor(sc, 8);
    sc += __shfl_xor(sc, 16);
    sc += __shfl_xor(sc, 32);
    if (lane < 8) {
      bool valid = (lane < nq) && (w <= (lane >> 1));   // causal
      S[w][lane] = valid ? sc : -1e30f;
    }
  }
  __syncthreads();

  // per-qv flash merge with existing partial (M1,L1)
  if (tid < 8) {
    if (tid < nq) {
      int pidx = (((b * HKn + hk) * NCHUNK + slot) << 3) + tid;
      float M1 = part_ml[pidx * 2];
      float L1 = part_ml[pidx * 2 + 1];
      float m2 = -1e30f;
      for (int j = 0; j < q_cnt; ++j) m2 = fmaxf(m2, S[j][tid]);
      float M = fmaxf(M1, m2);
      float e1 = __expf(M1 - M);
      float l2 = 0.f;
      for (int j = 0; j < q_cnt; ++j) {
        float p = __expf(S[j][tid] - M);
        pf[j][tid] = p;
        l2 += p;
      }
      e1s[tid] = e1;
      part_ml[pidx * 2] = M;
      part_ml[pidx * 2 + 1] = e1 * L1 + l2;
    } else {
      e1s[tid] = 0.f;
    }
  }
  __syncthreads();

  // rescale old o and add new-token PV
  for (int i = tid; i < 2048; i += 256) {
    int qv = i >> 8, d = i & 255;
    if (qv < nq) {
      size_t oidx = (size_t)((((b * HKn + hk) * NCHUNK + slot) << 3) + qv) * 256 + d;
      float acc = e1s[qv] * part_o[oidx];
      for (int j = 0; j < q_cnt; ++j)
        acc = fmaf(pf[j][qv], vbuf[(size_t)(q0 + j) * 2048 + (hk << 8) + d], acc);
      part_o[oidx] = acc;
    }
  }
}

// ---------------- k4: combine chunk partials ----------------
// grid 1024 = b(16)*qtok(4)*h(16), block 64
__global__ __launch_bounds__(64) void k4_attn_reduce(
    const float* __restrict__ part_o, const float* __restrict__ part_ml,
    const int* __restrict__ q_start, const int* __restrict__ q_lens,
    const int* __restrict__ kv_lens, float* __restrict__ attn_out) {
  const int h = blockIdx.x & 15;
  const int qtok = (blockIdx.x >> 4) & 3;
  const int b = blockIdx.x >> 6;
  const int q_cnt = q_lens[b];
  if (qtok >= q_cnt) return;
  const int hist = kv_lens[b] - q_cnt;
  const int nparts = (hist + 127) >> 7;   // new tokens merged into last slot
  const int qv = qtok * 2 + (h & 1);
  const int hk = h >> 1;
  const int lane = threadIdx.x;
  const int pbase = ((b * HKn + hk) * NCHUNK) << 3;
  float2 mls[16];
#pragma unroll
  for (int i = 0; i < 16; ++i)
    if (i < nparts)
      mls[i] = *reinterpret_cast<const float2*>(&part_ml[(size_t)(pbase + (i << 3) + qv) * 2]);
  float M = -1e30f;
#pragma unroll
  for (int i = 0; i < 16; ++i)
    if (i < nparts) M = fmaxf(M, mls[i].x);
  float4 o = make_float4(0.f, 0.f, 0.f, 0.f);
  float L = 0.f;
#pragma unroll
  for (int i = 0; i < 16; ++i)
    if (i < nparts) {
      float corr = __expf(mls[i].x - M);
      L += corr * mls[i].y;
      float4 pv = *reinterpret_cast<const float4*>(
          &part_o[(size_t)(pbase + (i << 3) + qv) * 256 + (lane << 2)]);
      o.x = fmaf(corr, pv.x, o.x);
      o.y = fmaf(corr, pv.y, o.y);
      o.z = fmaf(corr, pv.z, o.z);
      o.w = fmaf(corr, pv.w, o.w);
    }
  float inv = 1.0f / L;
  int tr = q_start[b] + qtok;
  float4 res = make_float4(o.x * inv, o.y * inv, o.z * inv, o.w * inv);
  *reinterpret_cast<float4*>(&attn_out[((size_t)tr * 16 + h) * 256 + (lane << 2)]) = res;
}

// ---------------- k5: output GEMM partial (attn @ Wo) ----------------
// grid 384 = 12 col-tiles(256) * 32 k-splits(128), block 256
__global__ __launch_bounds__(256) void k5_out_gemm(
    const float* __restrict__ ain, const float* __restrict__ Wo,
    float* __restrict__ part2) {
  const int tile = blockIdx.x % 12;
  const int ks = blockIdx.x / 12;
  const int c0 = tile << 8;
  const int kbase = ks << 7;
  const int cq = (threadIdx.x & 63) << 2;
  const int r0 = (threadIdx.x >> 6) * 10;
  __shared__ float h_lds[40][64];
  float acc[10][4];
#pragma unroll
  for (int r = 0; r < 10; ++r) { acc[r][0]=0.f; acc[r][1]=0.f; acc[r][2]=0.f; acc[r][3]=0.f; }
  for (int kc = 0; kc < 128; kc += 64) {
    __syncthreads();
    for (int i = threadIdx.x; i < 2560; i += 256) {
      int t = i >> 6, kk = i & 63;
      h_lds[t][kk] = ain[(size_t)t * 4096 + kbase + kc + kk];
    }
    __syncthreads();
    const float* wp = Wo + (size_t)(kbase + kc) * 3072 + c0 + cq;
#pragma unroll 8
    for (int kk = 0; kk < 64; ++kk) {
      float4 w4 = *reinterpret_cast<const float4*>(wp + (size_t)kk * 3072);
#pragma unroll
      for (int r = 0; r < 10; ++r) {
        float h = h_lds[r0 + r][kk];
        acc[r][0] = fmaf(h, w4.x, acc[r][0]);
        acc[r][1] = fmaf(h, w4.y, acc[r][1]);
        acc[r][2] = fmaf(h, w4.z, acc[r][2]);
        acc[r][3] = fmaf(h, w4.w, acc[r][3]);
      }
    }
  }
#pragma unroll
  for (int r = 0; r < 10; ++r) {
    int t = r0 + r;
    float4 v = make_float4(acc[r][0], acc[r][1], acc[r][2], acc[r][3]);
    *reinterpret_cast<float4*>(&part2[(size_t)(ks * TT + t) * 3072 + c0 + cq]) = v;
  }
}

// ---------------- k6: final k-split reduce -> d_out ----------------
__global__ __launch_bounds__(256) void k6_final_reduce(
    const float* __restrict__ part2, float* __restrict__ out) {
  const int idx = blockIdx.x * 256 + threadIdx.x;
  float s = 0.f;
#pragma unroll
  for (int ks = 0; ks < 32; ++ks) s += part2[(size_t)ks * 122880 + idx];
  out[idx] = s;
}

extern "C" void kernel_launch(void* const* d_in, const int* in_sizes, int n_in,
                              void* d_out, int out_size, void* d_ws, size_t ws_size,
                              hipStream_t stream) {
  const float* hs       = (const float*)d_in[0];
  const float* Wq       = (const float*)d_in[1];
  const float* Wk       = (const float*)d_in[2];
  const float* Wv       = (const float*)d_in[3];
  const float* Wo       = (const float*)d_in[4];
  const float* k_cache  = (const float*)d_in[5];
  const float* v_cache  = (const float*)d_in[6];
  const float* inv_freq = (const float*)d_in[7];
  const int*   pos_ids  = (const int*)d_in[8];
  const int*   q_start  = (const int*)d_in[9];
  const int*   q_lens   = (const int*)d_in[10];
  const int*   kv_lens  = (const int*)d_in[11];
  const int*   blk_off  = (const int*)d_in[12];

  float* ws = (float*)d_ws;
  float* qbuf     = ws;                   // 40*4096 = 163840
  float* kbuf     = ws + 163840;          // 40*2048
  float* vbuf     = ws + 245760;          // 40*2048
  float* attn_out = ws + 327680;          // 40*4096
  float* big      = ws + 491520;          // 5,242,880-float region (same as all prior rounds)
  float* part1q   = big;                  // 16*40*4096 = 2,621,440 (dead after k2q)
  float* part_o   = big;                  // 16384*256 = 4,194,304 (from kA on)
  float* part_ml  = big + 4194304;        // 32,768
  float* part1kv  = big + 4227072;        // 6*40*4096 = 983,040 (tail; coexists with part_o)
  float* part2    = big;                  // 32*40*3072 = 3,932,160 (after k4)
  float* out      = (float*)d_out;

  k1q <<<256, 256, 0, stream>>>(hs, Wq, part1q);
  k2q <<<640, 256, 0, stream>>>(part1q, inv_freq, pos_ids, qbuf);
  kA  <<<2144, 256, 0, stream>>>(hs, Wk, Wv, part1kv, qbuf, k_cache, v_cache,
                                 blk_off, q_start, q_lens, kv_lens, part_o, part_ml);
  k2kv<<<640, 256, 0, stream>>>(part1kv, inv_freq, pos_ids, kbuf, vbuf);
  k3new<<<128, 256, 0, stream>>>(qbuf, kbuf, vbuf, q_start, q_lens, kv_lens,
                                 part_o, part_ml);
  k4_attn_reduce<<<1024, 64, 0, stream>>>(part_o, part_ml, q_start, q_lens,
                                          kv_lens, attn_out);
  k5_out_gemm<<<384, 256, 0, stream>>>(attn_out, Wo, part2);
  k6_final_reduce<<<480, 256, 0, stream>>>(part2, out);
}

// Round 10
// 308.765 us; speedup vs baseline: 1.2129x; 1.2129x over previous
//
#include <hip/hip_runtime.h>
#include <math.h>

#define TT 40          // total query tokens (sum of q_seqlens)
#define NB 16          // batch
#define HQn 16         // query heads
#define HKn 8          // kv heads
#define Gn 2           // GQA group
#define Dn 256         // head dim
#define HID 3072
#define QKV_COLS 8192  // 4096 + 2048 + 2048
#define NCHUNK 16
#define CHUNKT 128

// ---------------- K1: QKV partial GEMM ----------------
// grid 512 = 32 col-tiles(256) * 16 k-splits(192), block 256  (r6 version)
__global__ __launch_bounds__(256) void k1_qkv_gemm(
    const float* __restrict__ hs, const float* __restrict__ Wq,
    const float* __restrict__ Wk, const float* __restrict__ Wv,
    float* __restrict__ part1) {
  const int tile = blockIdx.x & 31;
  const int ks = blockIdx.x >> 5;
  const int c0 = tile << 8;
  const float* W; int ld, cw0;
  if (tile < 16)      { W = Wq; ld = 4096; cw0 = c0; }
  else if (tile < 24) { W = Wk; ld = 2048; cw0 = c0 - 4096; }
  else                { W = Wv; ld = 2048; cw0 = c0 - 6144; }
  const int kbase = ks * 192;
  const int cq = (threadIdx.x & 63) << 2;
  const int r0 = (threadIdx.x >> 6) * 10;
  __shared__ float h_lds[40][64];   // [token][k] : coalesced staging
  float acc[10][4];
#pragma unroll
  for (int r = 0; r < 10; ++r) { acc[r][0]=0.f; acc[r][1]=0.f; acc[r][2]=0.f; acc[r][3]=0.f; }
  for (int kc = 0; kc < 192; kc += 64) {
    __syncthreads();
    for (int i = threadIdx.x; i < 2560; i += 256) {
      int t = i >> 6, kk = i & 63;
      h_lds[t][kk] = hs[t * HID + kbase + kc + kk];
    }
    __syncthreads();
    const float* wp = W + (size_t)(kbase + kc) * ld + cw0 + cq;
#pragma unroll 8
    for (int kk = 0; kk < 64; ++kk) {
      float4 w4 = *reinterpret_cast<const float4*>(wp + (size_t)kk * ld);
#pragma unroll
      for (int r = 0; r < 10; ++r) {
        float h = h_lds[r0 + r][kk];
        acc[r][0] = fmaf(h, w4.x, acc[r][0]);
        acc[r][1] = fmaf(h, w4.y, acc[r][1]);
        acc[r][2] = fmaf(h, w4.z, acc[r][2]);
        acc[r][3] = fmaf(h, w4.w, acc[r][3]);
      }
    }
  }
#pragma unroll
  for (int r = 0; r < 10; ++r) {
    int t = r0 + r;
    float4 v = make_float4(acc[r][0], acc[r][1], acc[r][2], acc[r][3]);
    *reinterpret_cast<float4*>(&part1[(size_t)(ks * TT + t) * QKV_COLS + c0 + cq]) = v;
  }
}

// ---------------- K2: k-split reduce + RoPE ----------------
// grid 1280 = 40 tokens * 32 tiles, block 256  (r6 version)
__global__ __launch_bounds__(256) void k2_reduce_rope(
    const float* __restrict__ part1, const float* __restrict__ inv_freq,
    const int* __restrict__ pos_ids,
    float* __restrict__ qbuf, float* __restrict__ kbuf, float* __restrict__ vbuf) {
  const int t = blockIdx.x >> 5;
  const int tile = blockIdx.x & 31;
  const int c = (tile << 8) + threadIdx.x;
  float s = 0.f;
#pragma unroll
  for (int ks = 0; ks < 16; ++ks) s += part1[(size_t)(ks * TT + t) * QKV_COLS + c];
  __shared__ float sl[256];
  sl[threadIdx.x] = s;
  __syncthreads();
  if (tile < 24) {   // q or k head: apply neox RoPE
    const int d = threadIdx.x;
    const int d2 = d & 127;
    float fr = (float)pos_ids[t] * inv_freq[d2];
    float cs = cosf(fr), sn = sinf(fr);
    float v = (d < 128) ? (sl[d] * cs - sl[d + 128] * sn)
                        : (sl[d] * cs + sl[d - 128] * sn);
    if (tile < 16) qbuf[t * 4096 + (tile << 8) + d] = v * 0.0625f;  // fold 1/sqrt(D)
    else           kbuf[t * 2048 + ((tile - 16) << 8) + d] = v;
  } else {
    vbuf[t * 2048 + ((tile - 24) << 8) + threadIdx.x] = s;
  }
}

// ---------------- K3: flash-decode attention partials (v10) ----------------
// r8 structure (17.9 KB LDS, qv-split PV, no obuf) with NO occupancy cap:
// VGPR free for register pipelining, LDS allows ~8 blocks/CU.
// grid 2048 = b(16)*hk(8)*chunk(16), block 256.
__global__ __launch_bounds__(256) void k3_attn_partial(
    const float* __restrict__ qbuf, const float* __restrict__ kbuf,
    const float* __restrict__ vbuf, const float* __restrict__ k_cache,
    const float* __restrict__ v_cache, const int* __restrict__ blk_off,
    const int* __restrict__ q_start, const int* __restrict__ q_lens,
    const int* __restrict__ kv_lens,
    float* __restrict__ part_o, float* __restrict__ part_ml) {
  const int chunk = blockIdx.x & 15;
  const int hk = (blockIdx.x >> 4) & 7;
  const int b = blockIdx.x >> 7;
  const int kv_len = kv_lens[b];
  const int cs0 = chunk * CHUNKT;
  if (cs0 >= kv_len) return;
  const int q_cnt = q_lens[b];
  const int hist = kv_len - q_cnt;
  const int q0 = q_start[b];
  const int nq = q_cnt * 2;

  __shared__ float q_lds[8][256];     // 8 KB
  __shared__ float S2[2][128][8];     // 8 KB: two half-sums -> p values
  __shared__ float red[32][8];        // 1 KB
  __shared__ float Mg[8];

  const int tid = threadIdx.x;
  const int w = tid >> 6;
  const int lane = tid & 63;
  const int tp = lane & 7;    // token quad within wave's 32 (score phase)
  const int qd = lane >> 3;   // interleaved 4-float dim slice (score phase)

  // chunk spans exactly 2 cache blocks: preload both -> pure-arith addressing
  const int bi = (b << 5) + (cs0 >> 6);
  const int blk0v = blk_off[bi];
  const int blk1v = blk_off[bi + 1];
  const float* kb0  = k_cache + ((size_t)blk0v << 17) + ((size_t)hk << 8);
  const float* kb1  = k_cache + ((size_t)blk1v << 17) + ((size_t)hk << 8);
  const float* vb0  = v_cache + ((size_t)blk0v << 17) + ((size_t)hk << 8);
  const float* vb1  = v_cache + ((size_t)blk1v << 17) + ((size_t)hk << 8);
  const float* knew = kbuf + ((size_t)q0 << 11) + ((size_t)hk << 8);
  const float* vnew = vbuf + ((size_t)q0 << 11) + ((size_t)hk << 8);

  auto rowK = [&](int s) -> const float* {
    if (s < hist) {
      const float* base = (s & 64) ? kb1 : kb0;
      return base + ((size_t)(s & 63) << 11);
    }
    return knew + ((size_t)(s - hist) << 11);
  };

  // stage Q (scale already folded): 8 qv rows x 256
  for (int i = tid; i < 2048; i += 256) {
    int qv = i >> 8, d = i & 255;
    int qtok = min(qv >> 1, q_cnt - 1);
    q_lds[qv][d] = qbuf[(size_t)(q0 + qtok) * 4096 + (hk * Gn + (qv & 1)) * 256 + d];
  }
  __syncthreads();

  const int sBeg = cs0 + (w << 5);

  // ---- score phase: lane owns 4 tokens x 32 dims (stride-32 interleave) ----
  const float* kr[4];
#pragma unroll
  for (int tt = 0; tt < 4; ++tt) {
    int s = sBeg + (tp << 2) + tt;
    int sc = s < kv_len ? s : kv_len - 1;   // clamp; masked in softmax
    kr[tt] = rowK(sc) + (qd << 2);
  }
  float acc[4][8];
#pragma unroll
  for (int tt = 0; tt < 4; ++tt)
#pragma unroll
    for (int qv = 0; qv < 8; ++qv) acc[tt][qv] = 0.f;

#pragma unroll
  for (int c = 0; c < 8; ++c) {
    float4 kf[4];
#pragma unroll
    for (int tt = 0; tt < 4; ++tt)
      kf[tt] = *reinterpret_cast<const float4*>(kr[tt] + (c << 5));
#pragma unroll
    for (int qv = 0; qv < 8; ++qv) {
      float4 qf = *reinterpret_cast<const float4*>(&q_lds[qv][(qd << 2) + (c << 5)]);
#pragma unroll
      for (int tt = 0; tt < 4; ++tt) {
        acc[tt][qv] = fmaf(qf.x, kf[tt].x, acc[tt][qv]);
        acc[tt][qv] = fmaf(qf.y, kf[tt].y, acc[tt][qv]);
        acc[tt][qv] = fmaf(qf.z, kf[tt].z, acc[tt][qv]);
        acc[tt][qv] = fmaf(qf.w, kf[tt].w, acc[tt][qv]);
      }
    }
  }
#pragma unroll
  for (int tt = 0; tt < 4; ++tt)
#pragma unroll
    for (int qv = 0; qv < 8; ++qv) {
      float v = acc[tt][qv];
      v += __shfl_xor(v, 8);
      v += __shfl_xor(v, 16);
      acc[tt][qv] = v;
    }
  if ((lane & 24) == 0) {
    const int h = lane >> 5;
#pragma unroll
    for (int tt = 0; tt < 4; ++tt) {
      int srel = (w << 5) + (tp << 2) + tt;
      *reinterpret_cast<float4*>(&S2[h][srel][0]) =
          make_float4(acc[tt][0], acc[tt][1], acc[tt][2], acc[tt][3]);
      *reinterpret_cast<float4*>(&S2[h][srel][4]) =
          make_float4(acc[tt][4], acc[tt][5], acc[tt][6], acc[tt][7]);
    }
  }
  __syncthreads();

  // ---- softmax over the whole chunk. thread: qv2 = tid&7, grp = tid>>3 ----
  const int qv2 = tid & 7;
  const int grp = tid >> 3;
  float sv[4];
  {
    float mloc = -1e30f;
#pragma unroll
    for (int t = 0; t < 4; ++t) {
      int sl = (grp << 2) + t;
      float v = S2[0][sl][qv2] + S2[1][sl][qv2];
      bool valid = (qv2 < nq) && ((cs0 + sl - hist) <= (qv2 >> 1));
      v = valid ? v : -1e30f;
      sv[t] = v;
      mloc = fmaxf(mloc, v);
    }
    red[grp][qv2] = mloc;
  }
  __syncthreads();
  if (tid < 8) {
    float M = -1e30f;
#pragma unroll
    for (int i = 0; i < 32; ++i) M = fmaxf(M, red[i][tid]);
    Mg[tid] = M;
  }
  __syncthreads();
  {
    float M = Mg[qv2];
    float lloc = 0.f;
#pragma unroll
    for (int t = 0; t < 4; ++t) {
      float p = __expf(sv[t] - M);
      S2[0][(grp << 2) + t][qv2] = p;
      lloc += p;
    }
    red[grp][qv2] = lloc;
  }
  __syncthreads();
  if (tid < 8) {
    float L = 0.f;
#pragma unroll
    for (int i = 0; i < 32; ++i) L += red[i][tid];
    int pidx = (((b * HKn + hk) * NCHUNK + chunk) << 3) + tid;
    part_ml[pidx * 2] = Mg[tid];
    part_ml[pidx * 2 + 1] = L;
  }

  // ---- PV phase: wave w owns qv pair (2w, 2w+1) over ALL chunk tokens ----
  const int qp = w << 1;
  const int d4 = lane << 2;
  float4 a0 = make_float4(0.f, 0.f, 0.f, 0.f);
  float4 a1 = make_float4(0.f, 0.f, 0.f, 0.f);
  const int lim = min(cs0 + CHUNKT, kv_len);

#define PV_STEP(VROW, SREL)                                          \
  {                                                                  \
    float4 vf = *reinterpret_cast<const float4*>(VROW);              \
    float2 pp = *reinterpret_cast<const float2*>(&S2[0][SREL][qp]);  \
    a0.x = fmaf(pp.x, vf.x, a0.x); a0.y = fmaf(pp.x, vf.y, a0.y);    \
    a0.z = fmaf(pp.x, vf.z, a0.z); a0.w = fmaf(pp.x, vf.w, a0.w);    \
    a1.x = fmaf(pp.y, vf.x, a1.x); a1.y = fmaf(pp.y, vf.y, a1.y);    \
    a1.z = fmaf(pp.y, vf.z, a1.z); a1.w = fmaf(pp.y, vf.w, a1.w);    \
  }

  {
    // region A: cache block 0
    int eA = min(min(cs0 + 64, hist), lim);
#pragma unroll 4
    for (int s = cs0; s < eA; ++s)
      PV_STEP(vb0 + ((size_t)(s & 63) << 11) + d4, s - cs0);
    // region B: cache block 1
    int eB = min(min(cs0 + 128, hist), lim);
#pragma unroll 4
    for (int s = cs0 + 64; s < eB; ++s)
      PV_STEP(vb1 + ((size_t)(s & 63) << 11) + d4, s - cs0);
    // region C: new tokens
    int bC = max(cs0, hist);
#pragma unroll
    for (int s = bC; s < lim; ++s)
      PV_STEP(vnew + ((size_t)(s - hist) << 11) + d4, s - cs0);
  }
#undef PV_STEP

  if (qp < nq) {
    int pidxb = (((b * HKn + hk) * NCHUNK + chunk) << 3) + qp;
    *reinterpret_cast<float4*>(&part_o[(size_t)pidxb * 256 + d4]) = a0;
    *reinterpret_cast<float4*>(&part_o[(size_t)(pidxb + 1) * 256 + d4]) = a1;
  }
}

// ---------------- K4: combine chunk partials ----------------
// grid 1024 = b(16)*qtok(4)*h(16), block 64
__global__ __launch_bounds__(64) void k4_attn_reduce(
    const float* __restrict__ part_o, const float* __restrict__ part_ml,
    const int* __restrict__ q_start, const int* __restrict__ q_lens,
    const int* __restrict__ kv_lens, float* __restrict__ attn_out) {
  const int h = blockIdx.x & 15;
  const int qtok = (blockIdx.x >> 4) & 3;
  const int b = blockIdx.x >> 6;
  const int q_cnt = q_lens[b];
  if (qtok >= q_cnt) return;
  const int kv_len = kv_lens[b];
  const int nparts = (kv_len + CHUNKT - 1) >> 7;
  const int qv = qtok * 2 + (h & 1);
  const int hk = h >> 1;
  const int lane = threadIdx.x;
  const int pbase = ((b * HKn + hk) * NCHUNK) << 3;
  float2 mls[16];
#pragma unroll
  for (int i = 0; i < 16; ++i)
    if (i < nparts)
      mls[i] = *reinterpret_cast<const float2*>(&part_ml[(size_t)(pbase + (i << 3) + qv) * 2]);
  float M = -1e30f;
#pragma unroll
  for (int i = 0; i < 16; ++i)
    if (i < nparts) M = fmaxf(M, mls[i].x);
  float4 o = make_float4(0.f, 0.f, 0.f, 0.f);
  float L = 0.f;
#pragma unroll
  for (int i = 0; i < 16; ++i)
    if (i < nparts) {
      float corr = __expf(mls[i].x - M);
      L += corr * mls[i].y;
      float4 pv = *reinterpret_cast<const float4*>(
          &part_o[(size_t)(pbase + (i << 3) + qv) * 256 + (lane << 2)]);
      o.x = fmaf(corr, pv.x, o.x);
      o.y = fmaf(corr, pv.y, o.y);
      o.z = fmaf(corr, pv.z, o.z);
      o.w = fmaf(corr, pv.w, o.w);
    }
  float inv = 1.0f / L;
  int tr = q_start[b] + qtok;
  float4 res = make_float4(o.x * inv, o.y * inv, o.z * inv, o.w * inv);
  *reinterpret_cast<float4*>(&attn_out[((size_t)tr * HQn + h) * 256 + (lane << 2)]) = res;
}

// ---------------- K5: output GEMM partial (attn @ Wo) ----------------
// grid 384 = 12 col-tiles(256) * 32 k-splits(128), block 256  (r6 version)
__global__ __launch_bounds__(256) void k5_out_gemm(
    const float* __restrict__ ain, const float* __restrict__ Wo,
    float* __restrict__ part2) {
  const int tile = blockIdx.x % 12;
  const int ks = blockIdx.x / 12;
  const int c0 = tile << 8;
  const int kbase = ks << 7;
  const int cq = (threadIdx.x & 63) << 2;
  const int r0 = (threadIdx.x >> 6) * 10;
  __shared__ float h_lds[40][64];
  float acc[10][4];
#pragma unroll
  for (int r = 0; r < 10; ++r) { acc[r][0]=0.f; acc[r][1]=0.f; acc[r][2]=0.f; acc[r][3]=0.f; }
  for (int kc = 0; kc < 128; kc += 64) {
    __syncthreads();
    for (int i = threadIdx.x; i < 2560; i += 256) {
      int t = i >> 6, kk = i & 63;
      h_lds[t][kk] = ain[(size_t)t * 4096 + kbase + kc + kk];
    }
    __syncthreads();
    const float* wp = Wo + (size_t)(kbase + kc) * 3072 + c0 + cq;
#pragma unroll 8
    for (int kk = 0; kk < 64; ++kk) {
      float4 w4 = *reinterpret_cast<const float4*>(wp + (size_t)kk * 3072);
#pragma unroll
      for (int r = 0; r < 10; ++r) {
        float h = h_lds[r0 + r][kk];
        acc[r][0] = fmaf(h, w4.x, acc[r][0]);
        acc[r][1] = fmaf(h, w4.y, acc[r][1]);
        acc[r][2] = fmaf(h, w4.z, acc[r][2]);
        acc[r][3] = fmaf(h, w4.w, acc[r][3]);
      }
    }
  }
#pragma unroll
  for (int r = 0; r < 10; ++r) {
    int t = r0 + r;
    float4 v = make_float4(acc[r][0], acc[r][1], acc[r][2], acc[r][3]);
    *reinterpret_cast<float4*>(&part2[(size_t)(ks * TT + t) * 3072 + c0 + cq]) = v;
  }
}

// ---------------- K6: final k-split reduce -> d_out ----------------
// grid 480, block 256  (40*3072 = 122880 outputs)
__global__ __launch_bounds__(256) void k6_final_reduce(
    const float* __restrict__ part2, float* __restrict__ out) {
  const int idx = blockIdx.x * 256 + threadIdx.x;
  float s = 0.f;
#pragma unroll
  for (int ks = 0; ks < 32; ++ks) s += part2[(size_t)ks * 122880 + idx];
  out[idx] = s;
}

extern "C" void kernel_launch(void* const* d_in, const int* in_sizes, int n_in,
                              void* d_out, int out_size, void* d_ws, size_t ws_size,
                              hipStream_t stream) {
  const float* hs       = (const float*)d_in[0];
  const float* Wq       = (const float*)d_in[1];
  const float* Wk       = (const float*)d_in[2];
  const float* Wv       = (const float*)d_in[3];
  const float* Wo       = (const float*)d_in[4];
  const float* k_cache  = (const float*)d_in[5];
  const float* v_cache  = (const float*)d_in[6];
  const float* inv_freq = (const float*)d_in[7];
  const int*   pos_ids  = (const int*)d_in[8];
  const int*   q_start  = (const int*)d_in[9];
  const int*   q_lens   = (const int*)d_in[10];
  const int*   kv_lens  = (const int*)d_in[11];
  const int*   blk_off  = (const int*)d_in[12];

  float* ws = (float*)d_ws;
  float* qbuf     = ws;                 // 40*4096
  float* kbuf     = ws + 163840;        // 40*2048
  float* vbuf     = ws + 245760;        // 40*2048
  float* attn_out = ws + 327680;        // 40*4096
  float* big      = ws + 491520;        // reused region
  float* part1    = big;                // 16*40*8192
  float* part_o   = big;                // 16384*256
  float* part_ml  = big + 4194304;      // 16384*2
  float* part2    = big;                // 32*40*3072
  float* out      = (float*)d_out;

  k1_qkv_gemm<<<512, 256, 0, stream>>>(hs, Wq, Wk, Wv, part1);
  k2_reduce_rope<<<1280, 256, 0, stream>>>(part1, inv_freq, pos_ids, qbuf, kbuf, vbuf);
  k3_attn_partial<<<2048, 256, 0, stream>>>(qbuf, kbuf, vbuf, k_cache, v_cache,
                                            blk_off, q_start, q_lens, kv_lens,
                                            part_o, part_ml);
  k4_attn_reduce<<<1024, 64, 0, stream>>>(part_o, part_ml, q_start, q_lens,
                                          kv_lens, attn_out);
  k5_out_gemm<<<384, 256, 0, stream>>>(attn_out, Wo, part2);
  k6_final_reduce<<<480, 256, 0, stream>>>(part2, out);
}

// Round 11
// 294.128 us; speedup vs baseline: 1.2732x; 1.0498x over previous
//
#include <hip/hip_runtime.h>
#include <math.h>

#define TT 40          // total query tokens (sum of q_seqlens)
#define NB 16          // batch
#define HQn 16         // query heads
#define HKn 8          // kv heads
#define Gn 2           // GQA group
#define Dn 256         // head dim
#define HID 3072
#define QKV_COLS 8192  // 4096 + 2048 + 2048
#define NPART 32       // 64-token parts per sequence (2048/64)

// intra-wave LDS handoff fence (guide rule #18)
#define WAVE_LDS_FENCE() do { \
    asm volatile("s_waitcnt lgkmcnt(0)" ::: "memory"); \
    __builtin_amdgcn_sched_barrier(0); \
  } while (0)

// ---------------- K1: QKV partial GEMM (r6 version) ----------------
// grid 512 = 32 col-tiles(256) * 16 k-splits(192), block 256
__global__ __launch_bounds__(256) void k1_qkv_gemm(
    const float* __restrict__ hs, const float* __restrict__ Wq,
    const float* __restrict__ Wk, const float* __restrict__ Wv,
    float* __restrict__ part1) {
  const int tile = blockIdx.x & 31;
  const int ks = blockIdx.x >> 5;
  const int c0 = tile << 8;
  const float* W; int ld, cw0;
  if (tile < 16)      { W = Wq; ld = 4096; cw0 = c0; }
  else if (tile < 24) { W = Wk; ld = 2048; cw0 = c0 - 4096; }
  else                { W = Wv; ld = 2048; cw0 = c0 - 6144; }
  const int kbase = ks * 192;
  const int cq = (threadIdx.x & 63) << 2;
  const int r0 = (threadIdx.x >> 6) * 10;
  __shared__ float h_lds[40][64];
  float acc[10][4];
#pragma unroll
  for (int r = 0; r < 10; ++r) { acc[r][0]=0.f; acc[r][1]=0.f; acc[r][2]=0.f; acc[r][3]=0.f; }
  for (int kc = 0; kc < 192; kc += 64) {
    __syncthreads();
    for (int i = threadIdx.x; i < 2560; i += 256) {
      int t = i >> 6, kk = i & 63;
      h_lds[t][kk] = hs[t * HID + kbase + kc + kk];
    }
    __syncthreads();
    const float* wp = W + (size_t)(kbase + kc) * ld + cw0 + cq;
#pragma unroll 8
    for (int kk = 0; kk < 64; ++kk) {
      float4 w4 = *reinterpret_cast<const float4*>(wp + (size_t)kk * ld);
#pragma unroll
      for (int r = 0; r < 10; ++r) {
        float h = h_lds[r0 + r][kk];
        acc[r][0] = fmaf(h, w4.x, acc[r][0]);
        acc[r][1] = fmaf(h, w4.y, acc[r][1]);
        acc[r][2] = fmaf(h, w4.z, acc[r][2]);
        acc[r][3] = fmaf(h, w4.w, acc[r][3]);
      }
    }
  }
#pragma unroll
  for (int r = 0; r < 10; ++r) {
    int t = r0 + r;
    float4 v = make_float4(acc[r][0], acc[r][1], acc[r][2], acc[r][3]);
    *reinterpret_cast<float4*>(&part1[(size_t)(ks * TT + t) * QKV_COLS + c0 + cq]) = v;
  }
}

// ---------------- K2: k-split reduce + RoPE (r6 version) ----------------
// grid 1280 = 40 tokens * 32 tiles, block 256
__global__ __launch_bounds__(256) void k2_reduce_rope(
    const float* __restrict__ part1, const float* __restrict__ inv_freq,
    const int* __restrict__ pos_ids,
    float* __restrict__ qbuf, float* __restrict__ kbuf, float* __restrict__ vbuf) {
  const int t = blockIdx.x >> 5;
  const int tile = blockIdx.x & 31;
  const int c = (tile << 8) + threadIdx.x;
  float s = 0.f;
#pragma unroll
  for (int ks = 0; ks < 16; ++ks) s += part1[(size_t)(ks * TT + t) * QKV_COLS + c];
  __shared__ float sl[256];
  sl[threadIdx.x] = s;
  __syncthreads();
  if (tile < 24) {
    const int d = threadIdx.x;
    const int d2 = d & 127;
    float fr = (float)pos_ids[t] * inv_freq[d2];
    float cs = cosf(fr), sn = sinf(fr);
    float v = (d < 128) ? (sl[d] * cs - sl[d + 128] * sn)
                        : (sl[d] * cs + sl[d - 128] * sn);
    if (tile < 16) qbuf[t * 4096 + (tile << 8) + d] = v * 0.0625f;  // fold 1/sqrt(D)
    else           kbuf[t * 2048 + ((tile - 16) << 8) + d] = v;
  } else {
    vbuf[t * 2048 + ((tile - 24) << 8) + threadIdx.x] = s;
  }
}

// ---------------- K3 v11: wave-independent 64-token flash parts ----------------
// grid 1024 = b(16)*hk(8)*seg(8); block 256 = 4 waves, each wave owns one
// 64-token part (= one cache block). No block barriers after Q staging.
// LDS 24.6 KB -> 6 blocks/CU (24 waves). nparts = ceil(kv_len/64) <= 32.
__global__ __launch_bounds__(256) void k3_attn_partial(
    const float* __restrict__ qbuf, const float* __restrict__ kbuf,
    const float* __restrict__ vbuf, const float* __restrict__ k_cache,
    const float* __restrict__ v_cache, const int* __restrict__ blk_off,
    const int* __restrict__ q_start, const int* __restrict__ q_lens,
    const int* __restrict__ kv_lens,
    float* __restrict__ part_o, float* __restrict__ part_ml) {
  const int seg = blockIdx.x & 7;
  const int hk = (blockIdx.x >> 3) & 7;
  const int b = blockIdx.x >> 6;
  const int kv_len = kv_lens[b];
  if ((seg << 8) >= kv_len) return;          // whole block idle (uniform)
  const int q_cnt = q_lens[b];
  const int hist = kv_len - q_cnt;
  const int q0 = q_start[b];
  const int nq = q_cnt * 2;

  __shared__ float q_lds[8][256];            //  8 KB (block-shared)
  __shared__ float S[4][2][64][8];           // 16 KB (wave-private slices)

  const int tid = threadIdx.x;
  const int w = tid >> 6;
  const int lane = tid & 63;

  // stage Q (scale folded): 8 qv rows x 256
  for (int i = tid; i < 2048; i += 256) {
    int qv = i >> 8, d = i & 255;
    int qtok = min(qv >> 1, q_cnt - 1);
    q_lds[qv][d] = qbuf[(size_t)(q0 + qtok) * 4096 + (hk * Gn + (qv & 1)) * 256 + d];
  }
  __syncthreads();                           // the ONLY block barrier

  const int part = (seg << 2) + w;           // 0..31
  const int sBeg = part << 6;
  if (sBeg >= kv_len) return;                // wave-level exit (no barriers below)

  const int blk = blk_off[(b << 5) + part];  // this wave's single cache block
  const float* kb   = k_cache + ((size_t)blk << 17) + ((size_t)hk << 8);
  const float* vb   = v_cache + ((size_t)blk << 17) + ((size_t)hk << 8);
  const float* knew = kbuf + ((size_t)q0 << 11) + ((size_t)hk << 8);
  const float* vnew = vbuf + ((size_t)q0 << 11) + ((size_t)hk << 8);

  const int tp = lane & 7;                   // token quad (score phase)
  const int qd = lane >> 3;                  // 4-float dim slice (score phase)

  // ---- score: 2 passes x 32 tokens; lane owns 4 tokens x 32 interleaved dims ----
#pragma unroll
  for (int pass = 0; pass < 2; ++pass) {
    const float* kr[4];
#pragma unroll
    for (int tt = 0; tt < 4; ++tt) {
      int s = sBeg + (pass << 5) + (tp << 2) + tt;
      int sc = s < kv_len ? s : kv_len - 1;  // clamp; masked in softmax
      const float* row = (sc < hist) ? (kb + ((size_t)(sc & 63) << 11))
                                     : (knew + ((size_t)(sc - hist) << 11));
      kr[tt] = row + (qd << 2);
    }
    float acc[4][8];
#pragma unroll
    for (int tt = 0; tt < 4; ++tt)
#pragma unroll
      for (int qv = 0; qv < 8; ++qv) acc[tt][qv] = 0.f;
#pragma unroll
    for (int c = 0; c < 8; ++c) {
      float4 kf[4];
#pragma unroll
      for (int tt = 0; tt < 4; ++tt)
        kf[tt] = *reinterpret_cast<const float4*>(kr[tt] + (c << 5));
#pragma unroll
      for (int qv = 0; qv < 8; ++qv) {
        float4 qf = *reinterpret_cast<const float4*>(&q_lds[qv][(qd << 2) + (c << 5)]);
#pragma unroll
        for (int tt = 0; tt < 4; ++tt) {
          acc[tt][qv] = fmaf(qf.x, kf[tt].x, acc[tt][qv]);
          acc[tt][qv] = fmaf(qf.y, kf[tt].y, acc[tt][qv]);
          acc[tt][qv] = fmaf(qf.z, kf[tt].z, acc[tt][qv]);
          acc[tt][qv] = fmaf(qf.w, kf[tt].w, acc[tt][qv]);
        }
      }
    }
#pragma unroll
    for (int tt = 0; tt < 4; ++tt)
#pragma unroll
      for (int qv = 0; qv < 8; ++qv) {
        float v = acc[tt][qv];
        v += __shfl_xor(v, 8);
        v += __shfl_xor(v, 16);
        acc[tt][qv] = v;                     // half-sums at qd=0 (h0) and qd=4 (h1)
      }
    if ((lane & 24) == 0) {
      const int h = lane >> 5;
#pragma unroll
      for (int tt = 0; tt < 4; ++tt) {
        int srel = (pass << 5) + (tp << 2) + tt;
        *reinterpret_cast<float4*>(&S[w][h][srel][0]) =
            make_float4(acc[tt][0], acc[tt][1], acc[tt][2], acc[tt][3]);
        *reinterpret_cast<float4*>(&S[w][h][srel][4]) =
            make_float4(acc[tt][4], acc[tt][5], acc[tt][6], acc[tt][7]);
      }
    }
  }
  WAVE_LDS_FENCE();   // intra-wave: score writes -> softmax reads

  // ---- wave-local softmax over 64 tokens x 8 qv ----
  // lane mapping: qv2 = lane>>3, grp = lane&7  (2-way-bank-free reads)
  const int qv2 = lane >> 3;
  const int grp = lane & 7;
  const int pidx8 = (((b * HKn + hk) * NPART + part) << 3);
  float sv[8];
  float mloc = -1e30f;
#pragma unroll
  for (int t = 0; t < 8; ++t) {
    int sl = (t << 3) + grp;
    float v = S[w][0][sl][qv2] + S[w][1][sl][qv2];
    int sAbs = sBeg + sl;
    bool valid = (qv2 < nq) && ((sAbs - hist) <= (qv2 >> 1));  // causal+tail mask
    v = valid ? v : -1e30f;
    sv[t] = v;
    mloc = fmaxf(mloc, v);
  }
  mloc = fmaxf(mloc, __shfl_xor(mloc, 1));
  mloc = fmaxf(mloc, __shfl_xor(mloc, 2));
  mloc = fmaxf(mloc, __shfl_xor(mloc, 4));
  const float M = mloc;
  float lloc = 0.f;
#pragma unroll
  for (int t = 0; t < 8; ++t) {
    float p = __expf(sv[t] - M);
    S[w][0][(t << 3) + grp][qv2] = p;        // p values in place
    lloc += p;
  }
  lloc += __shfl_xor(lloc, 1);
  lloc += __shfl_xor(lloc, 2);
  lloc += __shfl_xor(lloc, 4);
  if (grp == 0)
    *reinterpret_cast<float2*>(&part_ml[(size_t)(pidx8 + qv2) * 2]) =
        make_float2(M, lloc);
  WAVE_LDS_FENCE();   // intra-wave: p writes -> PV reads

  // ---- PV: lane owns 4 dims; wave streams its own 64 V rows ----
  const int d4 = lane << 2;
  float4 pacc[8];
#pragma unroll
  for (int q = 0; q < 8; ++q) pacc[q] = make_float4(0.f, 0.f, 0.f, 0.f);
  const int lim = min(sBeg + 64, kv_len);

#define PV_STEP(VROW, SREL)                                          \
  {                                                                  \
    float4 vf = *reinterpret_cast<const float4*>(VROW);              \
    float4 p0 = *reinterpret_cast<const float4*>(&S[w][0][SREL][0]); \
    float4 p1 = *reinterpret_cast<const float4*>(&S[w][0][SREL][4]); \
    float pr[8] = {p0.x, p0.y, p0.z, p0.w, p1.x, p1.y, p1.z, p1.w};  \
    _Pragma("unroll")                                                \
    for (int q = 0; q < 8; ++q) {                                    \
      pacc[q].x = fmaf(pr[q], vf.x, pacc[q].x);                      \
      pacc[q].y = fmaf(pr[q], vf.y, pacc[q].y);                      \
      pacc[q].z = fmaf(pr[q], vf.z, pacc[q].z);                      \
      pacc[q].w = fmaf(pr[q], vf.w, pacc[q].w);                      \
    }                                                                \
  }

  {
    int eH = min(lim, hist);                 // history region (this cache block)
#pragma unroll 4
    for (int s = sBeg; s < eH; ++s)
      PV_STEP(vb + ((size_t)(s & 63) << 11) + d4, s - sBeg);
    int bN = max(sBeg, hist);                // new-token region
    for (int s = bN; s < lim; ++s)
      PV_STEP(vnew + ((size_t)(s - hist) << 11) + d4, s - sBeg);
  }
#undef PV_STEP

#pragma unroll
  for (int q = 0; q < 8; ++q)
    *reinterpret_cast<float4*>(&part_o[(size_t)(pidx8 + q) * 256 + d4]) = pacc[q];
}

// ---------------- K4: combine part partials (up to 32) ----------------
// grid 1024 = b(16)*qtok(4)*h(16), block 64
__global__ __launch_bounds__(64) void k4_attn_reduce(
    const float* __restrict__ part_o, const float* __restrict__ part_ml,
    const int* __restrict__ q_start, const int* __restrict__ q_lens,
    const int* __restrict__ kv_lens, float* __restrict__ attn_out) {
  const int h = blockIdx.x & 15;
  const int qtok = (blockIdx.x >> 4) & 3;
  const int b = blockIdx.x >> 6;
  const int q_cnt = q_lens[b];
  if (qtok >= q_cnt) return;
  const int kv_len = kv_lens[b];
  const int nparts = (kv_len + 63) >> 6;
  const int qv = qtok * 2 + (h & 1);
  const int hk = h >> 1;
  const int lane = threadIdx.x;
  const int pbase = ((b * HKn + hk) * NPART) << 3;
  float M = -1e30f;
#pragma unroll 4
  for (int i = 0; i < nparts; ++i)
    M = fmaxf(M, part_ml[(size_t)(pbase + (i << 3) + qv) * 2]);
  float4 o = make_float4(0.f, 0.f, 0.f, 0.f);
  float L = 0.f;
#pragma unroll 4
  for (int i = 0; i < nparts; ++i) {
    float2 ml = *reinterpret_cast<const float2*>(
        &part_ml[(size_t)(pbase + (i << 3) + qv) * 2]);
    float corr = __expf(ml.x - M);
    L += corr * ml.y;
    float4 pv = *reinterpret_cast<const float4*>(
        &part_o[(size_t)(pbase + (i << 3) + qv) * 256 + (lane << 2)]);
    o.x = fmaf(corr, pv.x, o.x);
    o.y = fmaf(corr, pv.y, o.y);
    o.z = fmaf(corr, pv.z, o.z);
    o.w = fmaf(corr, pv.w, o.w);
  }
  float inv = 1.0f / L;
  int tr = q_start[b] + qtok;
  float4 res = make_float4(o.x * inv, o.y * inv, o.z * inv, o.w * inv);
  *reinterpret_cast<float4*>(&attn_out[((size_t)tr * HQn + h) * 256 + (lane << 2)]) = res;
}

// ---------------- K5: output GEMM partial (r6 version) ----------------
// grid 384 = 12 col-tiles(256) * 32 k-splits(128), block 256
__global__ __launch_bounds__(256) void k5_out_gemm(
    const float* __restrict__ ain, const float* __restrict__ Wo,
    float* __restrict__ part2) {
  const int tile = blockIdx.x % 12;
  const int ks = blockIdx.x / 12;
  const int c0 = tile << 8;
  const int kbase = ks << 7;
  const int cq = (threadIdx.x & 63) << 2;
  const int r0 = (threadIdx.x >> 6) * 10;
  __shared__ float h_lds[40][64];
  float acc[10][4];
#pragma unroll
  for (int r = 0; r < 10; ++r) { acc[r][0]=0.f; acc[r][1]=0.f; acc[r][2]=0.f; acc[r][3]=0.f; }
  for (int kc = 0; kc < 128; kc += 64) {
    __syncthreads();
    for (int i = threadIdx.x; i < 2560; i += 256) {
      int t = i >> 6, kk = i & 63;
      h_lds[t][kk] = ain[(size_t)t * 4096 + kbase + kc + kk];
    }
    __syncthreads();
    const float* wp = Wo + (size_t)(kbase + kc) * 3072 + c0 + cq;
#pragma unroll 8
    for (int kk = 0; kk < 64; ++kk) {
      float4 w4 = *reinterpret_cast<const float4*>(wp + (size_t)kk * 3072);
#pragma unroll
      for (int r = 0; r < 10; ++r) {
        float h = h_lds[r0 + r][kk];
        acc[r][0] = fmaf(h, w4.x, acc[r][0]);
        acc[r][1] = fmaf(h, w4.y, acc[r][1]);
        acc[r][2] = fmaf(h, w4.z, acc[r][2]);
        acc[r][3] = fmaf(h, w4.w, acc[r][3]);
      }
    }
  }
#pragma unroll
  for (int r = 0; r < 10; ++r) {
    int t = r0 + r;
    float4 v = make_float4(acc[r][0], acc[r][1], acc[r][2], acc[r][3]);
    *reinterpret_cast<float4*>(&part2[(size_t)(ks * TT + t) * 3072 + c0 + cq]) = v;
  }
}

// ---------------- K6: final k-split reduce -> d_out ----------------
// grid 480, block 256  (40*3072 = 122880 outputs)
__global__ __launch_bounds__(256) void k6_final_reduce(
    const float* __restrict__ part2, float* __restrict__ out) {
  const int idx = blockIdx.x * 256 + threadIdx.x;
  float s = 0.f;
#pragma unroll
  for (int ks = 0; ks < 32; ++ks) s += part2[(size_t)ks * 122880 + idx];
  out[idx] = s;
}

extern "C" void kernel_launch(void* const* d_in, const int* in_sizes, int n_in,
                              void* d_out, int out_size, void* d_ws, size_t ws_size,
                              hipStream_t stream) {
  const float* hs       = (const float*)d_in[0];
  const float* Wq       = (const float*)d_in[1];
  const float* Wk       = (const float*)d_in[2];
  const float* Wv       = (const float*)d_in[3];
  const float* Wo       = (const float*)d_in[4];
  const float* k_cache  = (const float*)d_in[5];
  const float* v_cache  = (const float*)d_in[6];
  const float* inv_freq = (const float*)d_in[7];
  const int*   pos_ids  = (const int*)d_in[8];
  const int*   q_start  = (const int*)d_in[9];
  const int*   q_lens   = (const int*)d_in[10];
  const int*   kv_lens  = (const int*)d_in[11];
  const int*   blk_off  = (const int*)d_in[12];

  // non-overlapping layout (ws is ~1 GiB per harness poison fills; we use 72.5 MB)
  float* ws = (float*)d_ws;
  float* qbuf     = ws;                  // 163,840
  float* kbuf     = ws + 163840;         //  81,920
  float* vbuf     = ws + 245760;         //  81,920
  float* attn_out = ws + 327680;         // 163,840
  float* part1    = ws + 491520;         // 5,242,880  (k1/k2 only)
  float* part_o   = ws + 5734400;        // 8,388,608  (128*32*8*256)
  float* part_ml  = ws + 14123008;       //    65,536
  float* part2    = ws + 14188544;       // 3,932,160  (k5/k6)
  float* out      = (float*)d_out;

  k1_qkv_gemm<<<512, 256, 0, stream>>>(hs, Wq, Wk, Wv, part1);
  k2_reduce_rope<<<1280, 256, 0, stream>>>(part1, inv_freq, pos_ids, qbuf, kbuf, vbuf);
  k3_attn_partial<<<1024, 256, 0, stream>>>(qbuf, kbuf, vbuf, k_cache, v_cache,
                                            blk_off, q_start, q_lens, kv_lens,
                                            part_o, part_ml);
  k4_attn_reduce<<<1024, 64, 0, stream>>>(part_o, part_ml, q_start, q_lens,
                                          kv_lens, attn_out);
  k5_out_gemm<<<384, 256, 0, stream>>>(attn_out, Wo, part2);
  k6_final_reduce<<<480, 256, 0, stream>>>(part2, out);
}

// Round 12
// 254.296 us; speedup vs baseline: 1.4726x; 1.1566x over previous
//
#include <hip/hip_runtime.h>
#include <math.h>

#define TT 40          // total query tokens (sum of q_seqlens)
#define NB 16          // batch
#define HQn 16         // query heads
#define HKn 8          // kv heads
#define Gn 2           // GQA group
#define Dn 256         // head dim
#define HID 3072
#define QKV_COLS 8192  // 4096 + 2048 + 2048
#define NPART 32       // 64-token parts per sequence (2048/64)

// intra-wave LDS handoff fence (guide rule #18)
#define WAVE_LDS_FENCE() do { \
    asm volatile("s_waitcnt lgkmcnt(0)" ::: "memory"); \
    __builtin_amdgcn_sched_barrier(0); \
  } while (0)

// ---------------- K1: QKV partial GEMM ----------------
// grid 512 = 32 col-tiles(256) * 16 k-splits(192), block 256
// r6 mapping (10 rows x 4 cols, coalesced W) but h via broadcast ds_read_b128.
__global__ __launch_bounds__(256) void k1_qkv_gemm(
    const float* __restrict__ hs, const float* __restrict__ Wq,
    const float* __restrict__ Wk, const float* __restrict__ Wv,
    float* __restrict__ part1) {
  const int tile = blockIdx.x & 31;
  const int ks = blockIdx.x >> 5;
  const int c0 = tile << 8;
  const float* W; int ld, cw0;
  if (tile < 16)      { W = Wq; ld = 4096; cw0 = c0; }
  else if (tile < 24) { W = Wk; ld = 2048; cw0 = c0 - 4096; }
  else                { W = Wv; ld = 2048; cw0 = c0 - 6144; }
  const int kbase = ks * 192;
  const int cq = (threadIdx.x & 63) << 2;
  const int r0 = (threadIdx.x >> 6) * 10;
  __shared__ float h_lds[40][64];
  float acc[10][4];
#pragma unroll
  for (int r = 0; r < 10; ++r) { acc[r][0]=0.f; acc[r][1]=0.f; acc[r][2]=0.f; acc[r][3]=0.f; }
  for (int kc = 0; kc < 192; kc += 64) {
    __syncthreads();
    for (int i = threadIdx.x; i < 2560; i += 256) {
      int t = i >> 6, kk = i & 63;
      h_lds[t][kk] = hs[t * HID + kbase + kc + kk];
    }
    __syncthreads();
    const float* wp = W + (size_t)(kbase + kc) * ld + cw0 + cq;
#pragma unroll 2
    for (int k4 = 0; k4 < 16; ++k4) {
      float4 h4[10];
#pragma unroll
      for (int r = 0; r < 10; ++r)   // wave-uniform rows -> broadcast b128
        h4[r] = *reinterpret_cast<const float4*>(&h_lds[r0 + r][k4 << 2]);
#pragma unroll
      for (int j = 0; j < 4; ++j) {
        float4 w4 = *reinterpret_cast<const float4*>(wp + (size_t)((k4 << 2) + j) * ld);
#pragma unroll
        for (int r = 0; r < 10; ++r) {
          float hv = (j == 0) ? h4[r].x : (j == 1) ? h4[r].y
                   : (j == 2) ? h4[r].z : h4[r].w;
          acc[r][0] = fmaf(hv, w4.x, acc[r][0]);
          acc[r][1] = fmaf(hv, w4.y, acc[r][1]);
          acc[r][2] = fmaf(hv, w4.z, acc[r][2]);
          acc[r][3] = fmaf(hv, w4.w, acc[r][3]);
        }
      }
    }
  }
#pragma unroll
  for (int r = 0; r < 10; ++r) {
    int t = r0 + r;
    float4 v = make_float4(acc[r][0], acc[r][1], acc[r][2], acc[r][3]);
    *reinterpret_cast<float4*>(&part1[(size_t)(ks * TT + t) * QKV_COLS + c0 + cq]) = v;
  }
}

// ---------------- K2: k-split reduce + RoPE (r6 version) ----------------
// grid 1280 = 40 tokens * 32 tiles, block 256
__global__ __launch_bounds__(256) void k2_reduce_rope(
    const float* __restrict__ part1, const float* __restrict__ inv_freq,
    const int* __restrict__ pos_ids,
    float* __restrict__ qbuf, float* __restrict__ kbuf, float* __restrict__ vbuf) {
  const int t = blockIdx.x >> 5;
  const int tile = blockIdx.x & 31;
  const int c = (tile << 8) + threadIdx.x;
  float s = 0.f;
#pragma unroll
  for (int ks = 0; ks < 16; ++ks) s += part1[(size_t)(ks * TT + t) * QKV_COLS + c];
  __shared__ float sl[256];
  sl[threadIdx.x] = s;
  __syncthreads();
  if (tile < 24) {
    const int d = threadIdx.x;
    const int d2 = d & 127;
    float fr = (float)pos_ids[t] * inv_freq[d2];
    float cs = cosf(fr), sn = sinf(fr);
    float v = (d < 128) ? (sl[d] * cs - sl[d + 128] * sn)
                        : (sl[d] * cs + sl[d - 128] * sn);
    if (tile < 16) qbuf[t * 4096 + (tile << 8) + d] = v * 0.0625f;  // fold 1/sqrt(D)
    else           kbuf[t * 2048 + ((tile - 16) << 8) + d] = v;
  } else {
    vbuf[t * 2048 + ((tile - 24) << 8) + threadIdx.x] = s;
  }
}

// ---------------- K3 v12: wave-independent parts + pipelined score loads ----
// grid 1024 = b(16)*hk(8)*seg(8); block 256 = 4 waves, each wave owns one
// 64-token part (= one cache block). No block barriers after Q staging.
__global__ __launch_bounds__(256) void k3_attn_partial(
    const float* __restrict__ qbuf, const float* __restrict__ kbuf,
    const float* __restrict__ vbuf, const float* __restrict__ k_cache,
    const float* __restrict__ v_cache, const int* __restrict__ blk_off,
    const int* __restrict__ q_start, const int* __restrict__ q_lens,
    const int* __restrict__ kv_lens,
    float* __restrict__ part_o, float* __restrict__ part_ml) {
  const int seg = blockIdx.x & 7;
  const int hk = (blockIdx.x >> 3) & 7;
  const int b = blockIdx.x >> 6;
  const int kv_len = kv_lens[b];
  if ((seg << 8) >= kv_len) return;
  const int q_cnt = q_lens[b];
  const int hist = kv_len - q_cnt;
  const int q0 = q_start[b];
  const int nq = q_cnt * 2;

  __shared__ float q_lds[8][256];            //  8 KB (block-shared)
  __shared__ float S[4][2][64][8];           // 16 KB (wave-private slices)

  const int tid = threadIdx.x;
  const int w = tid >> 6;
  const int lane = tid & 63;

  for (int i = tid; i < 2048; i += 256) {
    int qv = i >> 8, d = i & 255;
    int qtok = min(qv >> 1, q_cnt - 1);
    q_lds[qv][d] = qbuf[(size_t)(q0 + qtok) * 4096 + (hk * Gn + (qv & 1)) * 256 + d];
  }
  __syncthreads();                           // the ONLY block barrier

  const int part = (seg << 2) + w;
  const int sBeg = part << 6;
  if (sBeg >= kv_len) return;

  const int blk = blk_off[(b << 5) + part];
  const float* kb   = k_cache + ((size_t)blk << 17) + ((size_t)hk << 8);
  const float* vb   = v_cache + ((size_t)blk << 17) + ((size_t)hk << 8);
  const float* knew = kbuf + ((size_t)q0 << 11) + ((size_t)hk << 8);
  const float* vnew = vbuf + ((size_t)q0 << 11) + ((size_t)hk << 8);

  const int tp = lane & 7;
  const int qd = lane >> 3;

  // ---- score: 2 passes x 32 tokens; 2-deep pipelined K loads ----
#pragma unroll
  for (int pass = 0; pass < 2; ++pass) {
    const float* kr[4];
#pragma unroll
    for (int tt = 0; tt < 4; ++tt) {
      int s = sBeg + (pass << 5) + (tp << 2) + tt;
      int sc = s < kv_len ? s : kv_len - 1;
      const float* row = (sc < hist) ? (kb + ((size_t)(sc & 63) << 11))
                                     : (knew + ((size_t)(sc - hist) << 11));
      kr[tt] = row + (qd << 2);
    }
    float acc[4][8];
#pragma unroll
    for (int tt = 0; tt < 4; ++tt)
#pragma unroll
      for (int qv = 0; qv < 8; ++qv) acc[tt][qv] = 0.f;

    float4 kf[2][4];
#pragma unroll
    for (int tt = 0; tt < 4; ++tt)
      kf[0][tt] = *reinterpret_cast<const float4*>(kr[tt]);
#pragma unroll
    for (int c = 0; c < 8; ++c) {
      if (c + 1 < 8) {                       // issue next chunk before this FMA block
#pragma unroll
        for (int tt = 0; tt < 4; ++tt)
          kf[(c + 1) & 1][tt] =
              *reinterpret_cast<const float4*>(kr[tt] + ((c + 1) << 5));
      }
      const float4* kc_ = kf[c & 1];
#pragma unroll
      for (int qv = 0; qv < 8; ++qv) {
        float4 qf = *reinterpret_cast<const float4*>(&q_lds[qv][(qd << 2) + (c << 5)]);
#pragma unroll
        for (int tt = 0; tt < 4; ++tt) {
          acc[tt][qv] = fmaf(qf.x, kc_[tt].x, acc[tt][qv]);
          acc[tt][qv] = fmaf(qf.y, kc_[tt].y, acc[tt][qv]);
          acc[tt][qv] = fmaf(qf.z, kc_[tt].z, acc[tt][qv]);
          acc[tt][qv] = fmaf(qf.w, kc_[tt].w, acc[tt][qv]);
        }
      }
    }
#pragma unroll
    for (int tt = 0; tt < 4; ++tt)
#pragma unroll
      for (int qv = 0; qv < 8; ++qv) {
        float v = acc[tt][qv];
        v += __shfl_xor(v, 8);
        v += __shfl_xor(v, 16);
        acc[tt][qv] = v;                     // half-sums at qd=0 (h0), qd=4 (h1)
      }
    if ((lane & 24) == 0) {
      const int h = lane >> 5;
#pragma unroll
      for (int tt = 0; tt < 4; ++tt) {
        int srel = (pass << 5) + (tp << 2) + tt;
        *reinterpret_cast<float4*>(&S[w][h][srel][0]) =
            make_float4(acc[tt][0], acc[tt][1], acc[tt][2], acc[tt][3]);
        *reinterpret_cast<float4*>(&S[w][h][srel][4]) =
            make_float4(acc[tt][4], acc[tt][5], acc[tt][6], acc[tt][7]);
      }
    }
  }
  WAVE_LDS_FENCE();

  // ---- wave-local softmax over 64 tokens x 8 qv ----
  const int qv2 = lane >> 3;
  const int grp = lane & 7;
  const int pidx8 = (((b * HKn + hk) * NPART + part) << 3);
  float sv[8];
  float mloc = -1e30f;
#pragma unroll
  for (int t = 0; t < 8; ++t) {
    int sl = (t << 3) + grp;
    float v = S[w][0][sl][qv2] + S[w][1][sl][qv2];
    int sAbs = sBeg + sl;
    bool valid = (qv2 < nq) && ((sAbs - hist) <= (qv2 >> 1));
    v = valid ? v : -1e30f;
    sv[t] = v;
    mloc = fmaxf(mloc, v);
  }
  mloc = fmaxf(mloc, __shfl_xor(mloc, 1));
  mloc = fmaxf(mloc, __shfl_xor(mloc, 2));
  mloc = fmaxf(mloc, __shfl_xor(mloc, 4));
  const float M = mloc;
  float lloc = 0.f;
#pragma unroll
  for (int t = 0; t < 8; ++t) {
    float p = __expf(sv[t] - M);
    S[w][0][(t << 3) + grp][qv2] = p;
    lloc += p;
  }
  lloc += __shfl_xor(lloc, 1);
  lloc += __shfl_xor(lloc, 2);
  lloc += __shfl_xor(lloc, 4);
  if (grp == 0)
    *reinterpret_cast<float2*>(&part_ml[(size_t)(pidx8 + qv2) * 2]) =
        make_float2(M, lloc);
  WAVE_LDS_FENCE();

  // ---- PV: lane owns 4 dims; wave streams its own 64 V rows ----
  const int d4 = lane << 2;
  float4 pacc[8];
#pragma unroll
  for (int q = 0; q < 8; ++q) pacc[q] = make_float4(0.f, 0.f, 0.f, 0.f);
  const int lim = min(sBeg + 64, kv_len);

#define PV_STEP(VROW, SREL)                                          \
  {                                                                  \
    float4 vf = *reinterpret_cast<const float4*>(VROW);              \
    float4 p0 = *reinterpret_cast<const float4*>(&S[w][0][SREL][0]); \
    float4 p1 = *reinterpret_cast<const float4*>(&S[w][0][SREL][4]); \
    float pr[8] = {p0.x, p0.y, p0.z, p0.w, p1.x, p1.y, p1.z, p1.w};  \
    _Pragma("unroll")                                                \
    for (int q = 0; q < 8; ++q) {                                    \
      pacc[q].x = fmaf(pr[q], vf.x, pacc[q].x);                      \
      pacc[q].y = fmaf(pr[q], vf.y, pacc[q].y);                      \
      pacc[q].z = fmaf(pr[q], vf.z, pacc[q].z);                      \
      pacc[q].w = fmaf(pr[q], vf.w, pacc[q].w);                      \
    }                                                                \
  }

  {
    int eH = min(lim, hist);
#pragma unroll 4
    for (int s = sBeg; s < eH; ++s)
      PV_STEP(vb + ((size_t)(s & 63) << 11) + d4, s - sBeg);
    int bN = max(sBeg, hist);
    for (int s = bN; s < lim; ++s)
      PV_STEP(vnew + ((size_t)(s - hist) << 11) + d4, s - sBeg);
  }
#undef PV_STEP

#pragma unroll
  for (int q = 0; q < 8; ++q)
    *reinterpret_cast<float4*>(&part_o[(size_t)(pidx8 + q) * 256 + d4]) = pacc[q];
}

// ---------------- K4: combine part partials (up to 32) ----------------
// grid 1024 = b(16)*qtok(4)*h(16), block 64
__global__ __launch_bounds__(64) void k4_attn_reduce(
    const float* __restrict__ part_o, const float* __restrict__ part_ml,
    const int* __restrict__ q_start, const int* __restrict__ q_lens,
    const int* __restrict__ kv_lens, float* __restrict__ attn_out) {
  const int h = blockIdx.x & 15;
  const int qtok = (blockIdx.x >> 4) & 3;
  const int b = blockIdx.x >> 6;
  const int q_cnt = q_lens[b];
  if (qtok >= q_cnt) return;
  const int kv_len = kv_lens[b];
  const int nparts = (kv_len + 63) >> 6;
  const int qv = qtok * 2 + (h & 1);
  const int hk = h >> 1;
  const int lane = threadIdx.x;
  const int pbase = ((b * HKn + hk) * NPART) << 3;
  float M = -1e30f;
#pragma unroll 4
  for (int i = 0; i < nparts; ++i)
    M = fmaxf(M, part_ml[(size_t)(pbase + (i << 3) + qv) * 2]);
  float4 o = make_float4(0.f, 0.f, 0.f, 0.f);
  float L = 0.f;
#pragma unroll 4
  for (int i = 0; i < nparts; ++i) {
    float2 ml = *reinterpret_cast<const float2*>(
        &part_ml[(size_t)(pbase + (i << 3) + qv) * 2]);
    float corr = __expf(ml.x - M);
    L += corr * ml.y;
    float4 pv = *reinterpret_cast<const float4*>(
        &part_o[(size_t)(pbase + (i << 3) + qv) * 256 + (lane << 2)]);
    o.x = fmaf(corr, pv.x, o.x);
    o.y = fmaf(corr, pv.y, o.y);
    o.z = fmaf(corr, pv.z, o.z);
    o.w = fmaf(corr, pv.w, o.w);
  }
  float inv = 1.0f / L;
  int tr = q_start[b] + qtok;
  float4 res = make_float4(o.x * inv, o.y * inv, o.z * inv, o.w * inv);
  *reinterpret_cast<float4*>(&attn_out[((size_t)tr * HQn + h) * 256 + (lane << 2)]) = res;
}

// ---------------- K5: output GEMM partial ----------------
// grid 384 = 12 col-tiles(256) * 32 k-splits(128), block 256; b128 h reads
__global__ __launch_bounds__(256) void k5_out_gemm(
    const float* __restrict__ ain, const float* __restrict__ Wo,
    float* __restrict__ part2) {
  const int tile = blockIdx.x % 12;
  const int ks = blockIdx.x / 12;
  const int c0 = tile << 8;
  const int kbase = ks << 7;
  const int cq = (threadIdx.x & 63) << 2;
  const int r0 = (threadIdx.x >> 6) * 10;
  __shared__ float h_lds[40][64];
  float acc[10][4];
#pragma unroll
  for (int r = 0; r < 10; ++r) { acc[r][0]=0.f; acc[r][1]=0.f; acc[r][2]=0.f; acc[r][3]=0.f; }
  for (int kc = 0; kc < 128; kc += 64) {
    __syncthreads();
    for (int i = threadIdx.x; i < 2560; i += 256) {
      int t = i >> 6, kk = i & 63;
      h_lds[t][kk] = ain[(size_t)t * 4096 + kbase + kc + kk];
    }
    __syncthreads();
    const float* wp = Wo + (size_t)(kbase + kc) * 3072 + c0 + cq;
#pragma unroll 2
    for (int k4 = 0; k4 < 16; ++k4) {
      float4 h4[10];
#pragma unroll
      for (int r = 0; r < 10; ++r)
        h4[r] = *reinterpret_cast<const float4*>(&h_lds[r0 + r][k4 << 2]);
#pragma unroll
      for (int j = 0; j < 4; ++j) {
        float4 w4 = *reinterpret_cast<const float4*>(wp + (size_t)((k4 << 2) + j) * 3072);
#pragma unroll
        for (int r = 0; r < 10; ++r) {
          float hv = (j == 0) ? h4[r].x : (j == 1) ? h4[r].y
                   : (j == 2) ? h4[r].z : h4[r].w;
          acc[r][0] = fmaf(hv, w4.x, acc[r][0]);
          acc[r][1] = fmaf(hv, w4.y, acc[r][1]);
          acc[r][2] = fmaf(hv, w4.z, acc[r][2]);
          acc[r][3] = fmaf(hv, w4.w, acc[r][3]);
        }
      }
    }
  }
#pragma unroll
  for (int r = 0; r < 10; ++r) {
    int t = r0 + r;
    float4 v = make_float4(acc[r][0], acc[r][1], acc[r][2], acc[r][3]);
    *reinterpret_cast<float4*>(&part2[(size_t)(ks * TT + t) * 3072 + c0 + cq]) = v;
  }
}

// ---------------- K6: final k-split reduce -> d_out ----------------
// grid 480, block 256  (40*3072 = 122880 outputs)
__global__ __launch_bounds__(256) void k6_final_reduce(
    const float* __restrict__ part2, float* __restrict__ out) {
  const int idx = blockIdx.x * 256 + threadIdx.x;
  float s = 0.f;
#pragma unroll
  for (int ks = 0; ks < 32; ++ks) s += part2[(size_t)ks * 122880 + idx];
  out[idx] = s;
}

extern "C" void kernel_launch(void* const* d_in, const int* in_sizes, int n_in,
                              void* d_out, int out_size, void* d_ws, size_t ws_size,
                              hipStream_t stream) {
  const float* hs       = (const float*)d_in[0];
  const float* Wq       = (const float*)d_in[1];
  const float* Wk       = (const float*)d_in[2];
  const float* Wv       = (const float*)d_in[3];
  const float* Wo       = (const float*)d_in[4];
  const float* k_cache  = (const float*)d_in[5];
  const float* v_cache  = (const float*)d_in[6];
  const float* inv_freq = (const float*)d_in[7];
  const int*   pos_ids  = (const int*)d_in[8];
  const int*   q_start  = (const int*)d_in[9];
  const int*   q_lens   = (const int*)d_in[10];
  const int*   kv_lens  = (const int*)d_in[11];
  const int*   blk_off  = (const int*)d_in[12];

  float* ws = (float*)d_ws;
  float* qbuf     = ws;                  // 163,840
  float* kbuf     = ws + 163840;         //  81,920
  float* vbuf     = ws + 245760;         //  81,920
  float* attn_out = ws + 327680;         // 163,840
  float* part1    = ws + 491520;         // 5,242,880  (k1/k2 only)
  float* part_o   = ws + 5734400;        // 8,388,608  (128*32*8*256)
  float* part_ml  = ws + 14123008;       //    65,536
  float* part2    = ws + 14188544;       // 3,932,160  (k5/k6)
  float* out      = (float*)d_out;

  k1_qkv_gemm<<<512, 256, 0, stream>>>(hs, Wq, Wk, Wv, part1);
  k2_reduce_rope<<<1280, 256, 0, stream>>>(part1, inv_freq, pos_ids, qbuf, kbuf, vbuf);
  k3_attn_partial<<<1024, 256, 0, stream>>>(qbuf, kbuf, vbuf, k_cache, v_cache,
                                            blk_off, q_start, q_lens, kv_lens,
                                            part_o, part_ml);
  k4_attn_reduce<<<1024, 64, 0, stream>>>(part_o, part_ml, q_start, q_lens,
                                          kv_lens, attn_out);
  k5_out_gemm<<<384, 256, 0, stream>>>(attn_out, Wo, part2);
  k6_final_reduce<<<480, 256, 0, stream>>>(part2, out);
}